// Round 1
// baseline (274.423 us; speedup 1.0000x reference)
//
#include <hip/hip_runtime.h>
#include <hip/hip_bf16.h>
#include <cstdint>

#define T_TOK 1024
#define H_DIM 1024
#define I_DIM 512
#define E_NUM 16
#define TOPK  4

typedef __bf16 bf16;
typedef __bf16 bf16x8 __attribute__((ext_vector_type(8)));
typedef float  f32x4  __attribute__((ext_vector_type(4)));

// ---------------- init: zero out, reset counts, build shared-expert list ----------------
__global__ void init_kernel(float* __restrict__ out, int* __restrict__ counts,
                            int* __restrict__ tok, float* __restrict__ wt,
                            int* __restrict__ slot) {
  int i = blockIdx.x * 256 + threadIdx.x;   // 0..262143
  f32x4* o4 = (f32x4*)out;                  // 1M floats = 262144 float4
  o4[i] = f32x4{0.f, 0.f, 0.f, 0.f};
  if (i < 32) counts[i] = (i == E_NUM) ? T_TOK : 0;
  if (i < T_TOK) {
    tok [E_NUM * T_TOK + i] = i;
    wt  [E_NUM * T_TOK + i] = 1.0f;
    slot[E_NUM * T_TOK + i] = T_TOK * TOPK + i;
  }
}

// ---------------- router: sigmoid scores, top-4, renorm, append to expert lists ----------------
__global__ void router_kernel(const float* __restrict__ x, const float* __restrict__ gw,
                              int* __restrict__ counts, int* __restrict__ tok,
                              float* __restrict__ wt, int* __restrict__ slot) {
  const int t = blockIdx.x;
  const int lane = threadIdx.x;
  const float* xr = x + (size_t)t * H_DIM;
  float xv[16];
#pragma unroll
  for (int j = 0; j < 16; ++j) xv[j] = xr[lane + 64 * j];

  float score = -1e30f;  // lanes >= E_NUM keep -inf
  for (int e = 0; e < E_NUM; ++e) {
    const float* gr = gw + (size_t)e * H_DIM;
    float p = 0.f;
#pragma unroll
    for (int j = 0; j < 16; ++j) p += xv[j] * gr[lane + 64 * j];
#pragma unroll
    for (int off = 32; off > 0; off >>= 1) p += __shfl_xor(p, off);
    if (lane == e) score = 1.f / (1.f + __expf(-p));
  }
  // top-4 via 4 argmax reductions across the wave
  float rem = score;
  float vals[TOPK]; int idx[TOPK];
#pragma unroll
  for (int k = 0; k < TOPK; ++k) {
    float m = rem; int mi = lane;
#pragma unroll
    for (int off = 32; off > 0; off >>= 1) {
      float om = __shfl_xor(m, off);
      int   oi = __shfl_xor(mi, off);
      if (om > m || (om == m && oi < mi)) { m = om; mi = oi; }
    }
    vals[k] = m; idx[k] = mi;
    if (lane == mi) rem = -2e30f;
  }
  if (lane == 0) {
    float inv = 1.f / (vals[0] + vals[1] + vals[2] + vals[3]);
#pragma unroll
    for (int k = 0; k < TOPK; ++k) {
      int e = idx[k];
      int pos = atomicAdd(&counts[e], 1);
      tok [e * T_TOK + pos] = t;
      wt  [e * T_TOK + pos] = vals[k] * inv;
      slot[e * T_TOK + pos] = t * TOPK + k;
    }
  }
}

// ---------------- GEMM1: gathered X [cnt,1024] @ Wgu [1024,1024] -> swiglu -> h bf16 ----------------
__global__ __launch_bounds__(256, 2)
void gemm1_kernel(const float* __restrict__ x, const float* __restrict__ wgu,
                  const float* __restrict__ sgu, const int* __restrict__ counts,
                  const int* __restrict__ tok, const int* __restrict__ slot,
                  bf16* __restrict__ hbuf) {
  const int e   = blockIdx.z;
  const int cnt = counts[e];
  const int rt  = blockIdx.y;
  if (rt * 64 >= cnt) return;
  const int nb = blockIdx.x * 64;  // output col base within I=512
  const float* B = (e < E_NUM) ? (wgu + (size_t)e * H_DIM * (2 * I_DIM)) : sgu;

  __shared__ __align__(16) bf16 sA [64 * 40];
  __shared__ __align__(16) bf16 sBg[64 * 40];
  __shared__ __align__(16) bf16 sBu[64 * 40];

  const int tid  = threadIdx.x;
  const int wave = tid >> 6, lane = tid & 63;
  const int wr = wave >> 1, wc = wave & 1;
  const int fr = lane & 15, kg = lane >> 4;

  f32x4 accg[2][2], accu[2][2];
#pragma unroll
  for (int i = 0; i < 2; ++i)
#pragma unroll
    for (int j = 0; j < 2; ++j) { accg[i][j] = f32x4{0,0,0,0}; accu[i][j] = f32x4{0,0,0,0}; }

  const int sm = tid >> 2, sk = (tid & 3) * 8;  // A staging: row, k-offset
  const int gm = rt * 64 + sm;
  const float* arow = nullptr;
  if (gm < cnt) arow = x + (size_t)tok[e * T_TOK + gm] * H_DIM;

  const int bk = tid >> 3, bn = (tid & 7) * 8;  // B staging: k-row, col-offset

  for (int k0 = 0; k0 < H_DIM; k0 += 32) {
    {  // stage A (fp32 -> bf16), row-major [64][32] pad 40
      bf16x8 pack;
      if (arow) {
        float4 f0 = *(const float4*)(arow + k0 + sk);
        float4 f1 = *(const float4*)(arow + k0 + sk + 4);
        pack[0]=(bf16)f0.x; pack[1]=(bf16)f0.y; pack[2]=(bf16)f0.z; pack[3]=(bf16)f0.w;
        pack[4]=(bf16)f1.x; pack[5]=(bf16)f1.y; pack[6]=(bf16)f1.z; pack[7]=(bf16)f1.w;
      } else {
#pragma unroll
        for (int j = 0; j < 8; ++j) pack[j] = (bf16)0.f;
      }
      *(bf16x8*)(sA + sm * 40 + sk) = pack;
    }
    {  // stage Bg/Bu transposed: sB[n][k]
      const float* br = B + (size_t)(k0 + bk) * (2 * I_DIM);
      float4 g0 = *(const float4*)(br + nb + bn);
      float4 g1 = *(const float4*)(br + nb + bn + 4);
      float4 u0 = *(const float4*)(br + I_DIM + nb + bn);
      float4 u1 = *(const float4*)(br + I_DIM + nb + bn + 4);
      float gv[8] = {g0.x,g0.y,g0.z,g0.w,g1.x,g1.y,g1.z,g1.w};
      float uv[8] = {u0.x,u0.y,u0.z,u0.w,u1.x,u1.y,u1.z,u1.w};
#pragma unroll
      for (int j = 0; j < 8; ++j) {
        sBg[(bn + j) * 40 + bk] = (bf16)gv[j];
        sBu[(bn + j) * 40 + bk] = (bf16)uv[j];
      }
    }
    __syncthreads();
    bf16x8 a0  = *(const bf16x8*)(sA  + (wr * 32      + fr) * 40 + kg * 8);
    bf16x8 a1  = *(const bf16x8*)(sA  + (wr * 32 + 16 + fr) * 40 + kg * 8);
    bf16x8 bg0 = *(const bf16x8*)(sBg + (wc * 32      + fr) * 40 + kg * 8);
    bf16x8 bg1 = *(const bf16x8*)(sBg + (wc * 32 + 16 + fr) * 40 + kg * 8);
    bf16x8 bu0 = *(const bf16x8*)(sBu + (wc * 32      + fr) * 40 + kg * 8);
    bf16x8 bu1 = *(const bf16x8*)(sBu + (wc * 32 + 16 + fr) * 40 + kg * 8);
    accg[0][0] = __builtin_amdgcn_mfma_f32_16x16x32_bf16(a0, bg0, accg[0][0], 0, 0, 0);
    accg[0][1] = __builtin_amdgcn_mfma_f32_16x16x32_bf16(a0, bg1, accg[0][1], 0, 0, 0);
    accg[1][0] = __builtin_amdgcn_mfma_f32_16x16x32_bf16(a1, bg0, accg[1][0], 0, 0, 0);
    accg[1][1] = __builtin_amdgcn_mfma_f32_16x16x32_bf16(a1, bg1, accg[1][1], 0, 0, 0);
    accu[0][0] = __builtin_amdgcn_mfma_f32_16x16x32_bf16(a0, bu0, accu[0][0], 0, 0, 0);
    accu[0][1] = __builtin_amdgcn_mfma_f32_16x16x32_bf16(a0, bu1, accu[0][1], 0, 0, 0);
    accu[1][0] = __builtin_amdgcn_mfma_f32_16x16x32_bf16(a1, bu0, accu[1][0], 0, 0, 0);
    accu[1][1] = __builtin_amdgcn_mfma_f32_16x16x32_bf16(a1, bu1, accu[1][1], 0, 0, 0);
    __syncthreads();
  }
  // epilogue: swiglu, scatter-store h[slot][col] as bf16
#pragma unroll
  for (int mi = 0; mi < 2; ++mi) {
#pragma unroll
    for (int j = 0; j < 4; ++j) {
      int row  = wr * 32 + mi * 16 + kg * 4 + j;
      int grow = rt * 64 + row;
      if (grow < cnt) {
        int sl = slot[e * T_TOK + grow];
        bf16* hr = hbuf + (size_t)sl * I_DIM;
#pragma unroll
        for (int ni = 0; ni < 2; ++ni) {
          int col = nb + wc * 32 + ni * 16 + fr;
          float g = accg[mi][ni][j], u = accu[mi][ni][j];
          float h = (g / (1.f + __expf(-g))) * u;
          hr[col] = (bf16)h;
        }
      }
    }
  }
}

// ---------------- GEMM2: gathered h [cnt,512] @ Wd [512,1024] -> weighted atomicAdd into out ----------------
__global__ __launch_bounds__(256, 2)
void gemm2_kernel(const bf16* __restrict__ hbuf, const float* __restrict__ wd,
                  const float* __restrict__ sd, const int* __restrict__ counts,
                  const int* __restrict__ tok, const float* __restrict__ wt,
                  const int* __restrict__ slot, float* __restrict__ out) {
  const int e   = blockIdx.z;
  const int cnt = counts[e];
  const int rt  = blockIdx.y;
  if (rt * 64 >= cnt) return;
  const int nb = blockIdx.x * 64;  // output col base within H=1024
  const float* B = (e < E_NUM) ? (wd + (size_t)e * I_DIM * H_DIM) : sd;

  __shared__ __align__(16) bf16 sA[64 * 40];
  __shared__ __align__(16) bf16 sB[64 * 40];

  const int tid  = threadIdx.x;
  const int wave = tid >> 6, lane = tid & 63;
  const int wr = wave >> 1, wc = wave & 1;
  const int fr = lane & 15, kg = lane >> 4;

  f32x4 acc[2][2];
#pragma unroll
  for (int i = 0; i < 2; ++i)
#pragma unroll
    for (int j = 0; j < 2; ++j) acc[i][j] = f32x4{0,0,0,0};

  const int sm = tid >> 2, sk = (tid & 3) * 8;
  const int gm = rt * 64 + sm;
  const bf16* arow = nullptr;
  if (gm < cnt) arow = hbuf + (size_t)slot[e * T_TOK + gm] * I_DIM;

  const int bk = tid >> 3, bn = (tid & 7) * 8;

  for (int k0 = 0; k0 < I_DIM; k0 += 32) {
    if (arow) {
      *(uint4*)(sA + sm * 40 + sk) = *(const uint4*)(arow + k0 + sk);
    } else {
      uint4 z; z.x = z.y = z.z = z.w = 0u;
      *(uint4*)(sA + sm * 40 + sk) = z;
    }
    {
      const float* br = B + (size_t)(k0 + bk) * H_DIM + nb;
      float4 f0 = *(const float4*)(br + bn);
      float4 f1 = *(const float4*)(br + bn + 4);
      float fv[8] = {f0.x,f0.y,f0.z,f0.w,f1.x,f1.y,f1.z,f1.w};
#pragma unroll
      for (int j = 0; j < 8; ++j) sB[(bn + j) * 40 + bk] = (bf16)fv[j];
    }
    __syncthreads();
    bf16x8 a0 = *(const bf16x8*)(sA + (wr * 32      + fr) * 40 + kg * 8);
    bf16x8 a1 = *(const bf16x8*)(sA + (wr * 32 + 16 + fr) * 40 + kg * 8);
    bf16x8 b0 = *(const bf16x8*)(sB + (wc * 32      + fr) * 40 + kg * 8);
    bf16x8 b1 = *(const bf16x8*)(sB + (wc * 32 + 16 + fr) * 40 + kg * 8);
    acc[0][0] = __builtin_amdgcn_mfma_f32_16x16x32_bf16(a0, b0, acc[0][0], 0, 0, 0);
    acc[0][1] = __builtin_amdgcn_mfma_f32_16x16x32_bf16(a0, b1, acc[0][1], 0, 0, 0);
    acc[1][0] = __builtin_amdgcn_mfma_f32_16x16x32_bf16(a1, b0, acc[1][0], 0, 0, 0);
    acc[1][1] = __builtin_amdgcn_mfma_f32_16x16x32_bf16(a1, b1, acc[1][1], 0, 0, 0);
    __syncthreads();
  }
#pragma unroll
  for (int mi = 0; mi < 2; ++mi) {
#pragma unroll
    for (int j = 0; j < 4; ++j) {
      int row  = wr * 32 + mi * 16 + kg * 4 + j;
      int grow = rt * 64 + row;
      if (grow < cnt) {
        int   t = tok[e * T_TOK + grow];
        float w = wt [e * T_TOK + grow];
        float* orow = out + (size_t)t * H_DIM;
#pragma unroll
        for (int ni = 0; ni < 2; ++ni) {
          int col = nb + wc * 32 + ni * 16 + fr;
          atomicAdd(orow + col, w * acc[mi][ni][j]);
        }
      }
    }
  }
}

extern "C" void kernel_launch(void* const* d_in, const int* in_sizes, int n_in,
                              void* d_out, int out_size, void* d_ws, size_t ws_size,
                              hipStream_t stream) {
  const float* x   = (const float*)d_in[0];
  const float* gw  = (const float*)d_in[1];
  const float* wgu = (const float*)d_in[2];
  const float* wd  = (const float*)d_in[3];
  const float* sgu = (const float*)d_in[4];
  const float* sd  = (const float*)d_in[5];
  float* out = (float*)d_out;

  char* ws = (char*)d_ws;
  int*   counts = (int*)  (ws);                       // 1 KB region
  int*   tok    = (int*)  (ws + 1024);                // 17*1024 ints
  float* wtA    = (float*)(ws + 1024 + 69632);        // 17*1024 floats
  int*   slotA  = (int*)  (ws + 1024 + 2 * 69632);    // 17*1024 ints
  bf16*  hbuf   = (bf16*) (ws + 209920);              // 5120 * 512 bf16 = 5.25 MB

  init_kernel<<<1024, 256, 0, stream>>>(out, counts, tok, wtA, slotA);
  router_kernel<<<T_TOK, 64, 0, stream>>>(x, gw, counts, tok, wtA, slotA);
  gemm1_kernel<<<dim3(8, 16, 17), 256, 0, stream>>>(x, wgu, sgu, counts, tok, slotA, hbuf);
  gemm2_kernel<<<dim3(16, 16, 17), 256, 0, stream>>>(hbuf, wd, sd, counts, tok, wtA, slotA, out);
}

// Round 2
// 190.486 us; speedup vs baseline: 1.4406x; 1.4406x over previous
//
#include <hip/hip_runtime.h>
#include <hip/hip_bf16.h>
#include <cstdint>

#define T_TOK 1024
#define H_DIM 1024
#define I_DIM 512
#define E_NUM 16
#define TOPK  4

typedef __bf16 bf16;
typedef __bf16 bf16x8 __attribute__((ext_vector_type(8)));
typedef float  f32x4  __attribute__((ext_vector_type(4)));

#define GLOAD16(g, l)                                                                   \
  __builtin_amdgcn_global_load_lds((const __attribute__((address_space(1))) void*)(g),  \
                                   (__attribute__((address_space(3))) void*)(l), 16, 0, 0)

// ---------------- init: zero out, reset counts, build shared-expert list ----------------
__global__ void init_kernel(float* __restrict__ out, int* __restrict__ counts,
                            int* __restrict__ tok, float* __restrict__ wt,
                            int* __restrict__ slot) {
  int i = blockIdx.x * 256 + threadIdx.x;   // 0..262143
  f32x4* o4 = (f32x4*)out;                  // 1M floats = 262144 float4
  o4[i] = f32x4{0.f, 0.f, 0.f, 0.f};
  if (i < 32) counts[i] = (i == E_NUM) ? T_TOK : 0;
  if (i < T_TOK) {
    tok [E_NUM * T_TOK + i] = i;
    wt  [E_NUM * T_TOK + i] = 1.0f;
    slot[E_NUM * T_TOK + i] = T_TOK * TOPK + i;
  }
}

// ---------------- convert x fp32 -> bf16 ----------------
__global__ void convx_kernel(const float* __restrict__ x, bf16* __restrict__ xb) {
  int i = blockIdx.x * 256 + threadIdx.x;   // 1M/8 = 131072 threads
  float4 f0 = ((const float4*)x)[i * 2];
  float4 f1 = ((const float4*)x)[i * 2 + 1];
  bf16x8 p;
  p[0]=(bf16)f0.x; p[1]=(bf16)f0.y; p[2]=(bf16)f0.z; p[3]=(bf16)f0.w;
  p[4]=(bf16)f1.x; p[5]=(bf16)f1.y; p[6]=(bf16)f1.z; p[7]=(bf16)f1.w;
  ((bf16x8*)xb)[i] = p;
}

// ---------------- transpose+convert: src fp32 [K][N] -> dst bf16 [N][K], per-mat z ----------------
__global__ void transpose_conv_kernel(const float* __restrict__ src, bf16* __restrict__ dst,
                                      int K, int N) {
  const float* s = src + (size_t)blockIdx.z * K * N;
  bf16* d = dst + (size_t)blockIdx.z * K * N;
  int n = blockIdx.x * 64 + (threadIdx.x & 63);
  int k = blockIdx.y * 32 + (threadIdx.x >> 6) * 8;
  bf16x8 p;
#pragma unroll
  for (int j = 0; j < 8; ++j) p[j] = (bf16)s[(size_t)(k + j) * N + n];
  *(bf16x8*)(d + (size_t)n * K + k) = p;
}

// ---------------- router: sigmoid scores, top-4, renorm, append to expert lists ----------------
__global__ void router_kernel(const float* __restrict__ x, const float* __restrict__ gw,
                              int* __restrict__ counts, int* __restrict__ tok,
                              float* __restrict__ wt, int* __restrict__ slot) {
  const int t = blockIdx.x;
  const int lane = threadIdx.x;
  const float* xr = x + (size_t)t * H_DIM;
  float xv[16];
#pragma unroll
  for (int j = 0; j < 16; ++j) xv[j] = xr[lane + 64 * j];

  float score = -1e30f;  // lanes >= E_NUM keep -inf
  for (int e = 0; e < E_NUM; ++e) {
    const float* gr = gw + (size_t)e * H_DIM;
    float p = 0.f;
#pragma unroll
    for (int j = 0; j < 16; ++j) p += xv[j] * gr[lane + 64 * j];
#pragma unroll
    for (int off = 32; off > 0; off >>= 1) p += __shfl_xor(p, off);
    if (lane == e) score = 1.f / (1.f + __expf(-p));
  }
  float rem = score;
  float vals[TOPK]; int idx[TOPK];
#pragma unroll
  for (int k = 0; k < TOPK; ++k) {
    float m = rem; int mi = lane;
#pragma unroll
    for (int off = 32; off > 0; off >>= 1) {
      float om = __shfl_xor(m, off);
      int   oi = __shfl_xor(mi, off);
      if (om > m || (om == m && oi < mi)) { m = om; mi = oi; }
    }
    vals[k] = m; idx[k] = mi;
    if (lane == mi) rem = -2e30f;
  }
  if (lane == 0) {
    float inv = 1.f / (vals[0] + vals[1] + vals[2] + vals[3]);
#pragma unroll
    for (int k = 0; k < TOPK; ++k) {
      int e = idx[k];
      int pos = atomicAdd(&counts[e], 1);
      tok [e * T_TOK + pos] = t;
      wt  [e * T_TOK + pos] = vals[k] * inv;
      slot[e * T_TOK + pos] = t * TOPK + k;
    }
  }
}

// ---------------- GEMM1: gathered Xb [cnt,1024] @ WguT -> swiglu -> h bf16 ----------------
// BM=64 tokens, BN=128 h-cols (128 gate rows + 128 up rows of W^T), BK=32.
__global__ __launch_bounds__(256, 2)
void gemm1_kernel(const bf16* __restrict__ xb, const bf16* __restrict__ wguT,
                  const bf16* __restrict__ sguT, const int* __restrict__ counts,
                  const int* __restrict__ tok, const int* __restrict__ slot,
                  bf16* __restrict__ hbuf) {
  const int e   = blockIdx.z;
  const int cnt = counts[e];
  const int rt  = blockIdx.y;
  if (rt * 64 >= cnt) return;
  const int nb = blockIdx.x * 128;  // h col base within I=512
  const bf16* BT = (e < E_NUM) ? (wguT + (size_t)e * (2 * I_DIM) * H_DIM) : sguT;

  __shared__ __align__(16) bf16 sA[64 * 32];    // [row][k]
  __shared__ __align__(16) bf16 sG[128 * 32];   // [gate col][k]
  __shared__ __align__(16) bf16 sU[128 * 32];   // [up col][k]

  const int tid = threadIdx.x, wave = tid >> 6, lane = tid & 63;
  const int wr = wave >> 1, wc = wave & 1;      // 2x2 wave grid over 64x128
  const int fr = lane & 15, kg = lane >> 4;
  const int lr = lane >> 2, lk = (lane & 3) * 8;  // staging: row-within-16, k-elem offset

  // staging source pointers (per lane); LDS dests (wave-uniform)
  int ar = rt * 64 + wave * 16 + lr;
  int arc = ar < cnt ? ar : cnt - 1;
  const bf16* aS  = xb + (size_t)tok[e * T_TOK + arc] * H_DIM + lk;
  const bf16* gS0 = BT + (size_t)(nb + wave * 32 + lr) * H_DIM + lk;
  const bf16* gS1 = gS0 + (size_t)16 * H_DIM;
  const bf16* uS0 = BT + (size_t)(I_DIM + nb + wave * 32 + lr) * H_DIM + lk;
  const bf16* uS1 = uS0 + (size_t)16 * H_DIM;
  bf16* aL  = sA + wave * 512;   // 16 rows * 32 k
  bf16* gL0 = sG + wave * 1024;  // 32 rows per wave, 2 instrs
  bf16* gL1 = gL0 + 512;
  bf16* uL0 = sU + wave * 1024;
  bf16* uL1 = uL0 + 512;

  f32x4 accg[2][4], accu[2][4];
#pragma unroll
  for (int i = 0; i < 2; ++i)
#pragma unroll
    for (int j = 0; j < 4; ++j) { accg[i][j] = f32x4{0,0,0,0}; accu[i][j] = f32x4{0,0,0,0}; }

  for (int k0 = 0; k0 < H_DIM; k0 += 32) {
    GLOAD16(aS  + k0, aL);
    GLOAD16(gS0 + k0, gL0);
    GLOAD16(gS1 + k0, gL1);
    GLOAD16(uS0 + k0, uL0);
    GLOAD16(uS1 + k0, uL1);
    __syncthreads();
    bf16x8 a0 = *(const bf16x8*)(sA + (wr * 32      + fr) * 32 + kg * 8);
    bf16x8 a1 = *(const bf16x8*)(sA + (wr * 32 + 16 + fr) * 32 + kg * 8);
    bf16x8 bg[4], bu[4];
#pragma unroll
    for (int ni = 0; ni < 4; ++ni) {
      bg[ni] = *(const bf16x8*)(sG + (wc * 64 + ni * 16 + fr) * 32 + kg * 8);
      bu[ni] = *(const bf16x8*)(sU + (wc * 64 + ni * 16 + fr) * 32 + kg * 8);
    }
#pragma unroll
    for (int ni = 0; ni < 4; ++ni) {
      accg[0][ni] = __builtin_amdgcn_mfma_f32_16x16x32_bf16(a0, bg[ni], accg[0][ni], 0, 0, 0);
      accg[1][ni] = __builtin_amdgcn_mfma_f32_16x16x32_bf16(a1, bg[ni], accg[1][ni], 0, 0, 0);
      accu[0][ni] = __builtin_amdgcn_mfma_f32_16x16x32_bf16(a0, bu[ni], accu[0][ni], 0, 0, 0);
      accu[1][ni] = __builtin_amdgcn_mfma_f32_16x16x32_bf16(a1, bu[ni], accu[1][ni], 0, 0, 0);
    }
    __syncthreads();
  }

  // epilogue: swiglu, scatter-store h[slot][col] as bf16
#pragma unroll
  for (int mi = 0; mi < 2; ++mi) {
#pragma unroll
    for (int j = 0; j < 4; ++j) {
      int grow = rt * 64 + wr * 32 + mi * 16 + kg * 4 + j;
      if (grow < cnt) {
        bf16* hr = hbuf + (size_t)slot[e * T_TOK + grow] * I_DIM;
#pragma unroll
        for (int ni = 0; ni < 4; ++ni) {
          float g = accg[mi][ni][j], u = accu[mi][ni][j];
          float h = (g / (1.f + __expf(-g))) * u;
          hr[nb + wc * 64 + ni * 16 + fr] = (bf16)h;
        }
      }
    }
  }
}

// ---------------- GEMM2: gathered h [cnt,512] @ WdT -> weighted atomicAdd into out ----------------
// BM=64, BN=128, BK=32.
__global__ __launch_bounds__(256, 2)
void gemm2_kernel(const bf16* __restrict__ hbuf, const bf16* __restrict__ wdT,
                  const bf16* __restrict__ sdT, const int* __restrict__ counts,
                  const int* __restrict__ tok, const float* __restrict__ wt,
                  const int* __restrict__ slot, float* __restrict__ out) {
  const int e   = blockIdx.z;
  const int cnt = counts[e];
  const int rt  = blockIdx.y;
  if (rt * 64 >= cnt) return;
  const int nb = blockIdx.x * 128;  // out col base within H=1024
  const bf16* BT = (e < E_NUM) ? (wdT + (size_t)e * H_DIM * I_DIM) : sdT;  // [H][I]

  __shared__ __align__(16) bf16 sA[64 * 32];
  __shared__ __align__(16) bf16 sB[128 * 32];

  const int tid = threadIdx.x, wave = tid >> 6, lane = tid & 63;
  const int wr = wave >> 1, wc = wave & 1;
  const int fr = lane & 15, kg = lane >> 4;
  const int lr = lane >> 2, lk = (lane & 3) * 8;

  int ar = rt * 64 + wave * 16 + lr;
  int arc = ar < cnt ? ar : cnt - 1;
  const bf16* aS  = hbuf + (size_t)slot[e * T_TOK + arc] * I_DIM + lk;
  const bf16* bS0 = BT + (size_t)(nb + wave * 32 + lr) * I_DIM + lk;
  const bf16* bS1 = bS0 + (size_t)16 * I_DIM;
  bf16* aL  = sA + wave * 512;
  bf16* bL0 = sB + wave * 1024;
  bf16* bL1 = bL0 + 512;

  f32x4 acc[2][4];
#pragma unroll
  for (int i = 0; i < 2; ++i)
#pragma unroll
    for (int j = 0; j < 4; ++j) acc[i][j] = f32x4{0,0,0,0};

  for (int k0 = 0; k0 < I_DIM; k0 += 32) {
    GLOAD16(aS  + k0, aL);
    GLOAD16(bS0 + k0, bL0);
    GLOAD16(bS1 + k0, bL1);
    __syncthreads();
    bf16x8 a0 = *(const bf16x8*)(sA + (wr * 32      + fr) * 32 + kg * 8);
    bf16x8 a1 = *(const bf16x8*)(sA + (wr * 32 + 16 + fr) * 32 + kg * 8);
    bf16x8 b[4];
#pragma unroll
    for (int ni = 0; ni < 4; ++ni)
      b[ni] = *(const bf16x8*)(sB + (wc * 64 + ni * 16 + fr) * 32 + kg * 8);
#pragma unroll
    for (int ni = 0; ni < 4; ++ni) {
      acc[0][ni] = __builtin_amdgcn_mfma_f32_16x16x32_bf16(a0, b[ni], acc[0][ni], 0, 0, 0);
      acc[1][ni] = __builtin_amdgcn_mfma_f32_16x16x32_bf16(a1, b[ni], acc[1][ni], 0, 0, 0);
    }
    __syncthreads();
  }

#pragma unroll
  for (int mi = 0; mi < 2; ++mi) {
#pragma unroll
    for (int j = 0; j < 4; ++j) {
      int grow = rt * 64 + wr * 32 + mi * 16 + kg * 4 + j;
      if (grow < cnt) {
        int   t = tok[e * T_TOK + grow];
        float w = wt [e * T_TOK + grow];
        float* orow = out + (size_t)t * H_DIM + nb + wc * 64 + fr;
#pragma unroll
        for (int ni = 0; ni < 4; ++ni)
          atomicAdd(orow + ni * 16, w * acc[mi][ni][j]);
      }
    }
  }
}

extern "C" void kernel_launch(void* const* d_in, const int* in_sizes, int n_in,
                              void* d_out, int out_size, void* d_ws, size_t ws_size,
                              hipStream_t stream) {
  const float* x   = (const float*)d_in[0];
  const float* gw  = (const float*)d_in[1];
  const float* wgu = (const float*)d_in[2];
  const float* wd  = (const float*)d_in[3];
  const float* sgu = (const float*)d_in[4];
  const float* sd  = (const float*)d_in[5];
  float* out = (float*)d_out;

  char* ws = (char*)d_ws;
  int*   counts = (int*)  (ws);
  int*   tok    = (int*)  (ws + 1024);
  float* wtA    = (float*)(ws + 70656);
  int*   slotA  = (int*)  (ws + 140288);
  bf16*  xb     = (bf16*) (ws + 212992);               // 2 MB
  bf16*  hbuf   = (bf16*) (ws + 2310144);              // 5.25 MB
  bf16*  wguT   = (bf16*) (ws + 7553024);              // 32 MB  [E][2I][H]
  bf16*  wdT    = (bf16*) (ws + 41107456);             // 16 MB  [E][H][I]
  bf16*  sguT   = (bf16*) (ws + 57884672);             // 2 MB   [2I][H]
  bf16*  sdT    = (bf16*) (ws + 59981824);             // 1 MB   [H][I]
  // total ws use ~61.0 MB

  init_kernel<<<1024, 256, 0, stream>>>(out, counts, tok, wtA, slotA);
  convx_kernel<<<512, 256, 0, stream>>>(x, xb);
  transpose_conv_kernel<<<dim3(16, 32, E_NUM), 256, 0, stream>>>(wgu, wguT, H_DIM, 2 * I_DIM);
  transpose_conv_kernel<<<dim3(16, 16, E_NUM), 256, 0, stream>>>(wd,  wdT,  I_DIM, H_DIM);
  transpose_conv_kernel<<<dim3(16, 32, 1),     256, 0, stream>>>(sgu, sguT, H_DIM, 2 * I_DIM);
  transpose_conv_kernel<<<dim3(16, 16, 1),     256, 0, stream>>>(sd,  sdT,  I_DIM, H_DIM);
  router_kernel<<<T_TOK, 64, 0, stream>>>(x, gw, counts, tok, wtA, slotA);
  gemm1_kernel<<<dim3(4, 16, 17), 256, 0, stream>>>(xb, wguT, sguT, counts, tok, slotA, hbuf);
  gemm2_kernel<<<dim3(8, 16, 17), 256, 0, stream>>>(hbuf, wdT, sdT, counts, tok, wtA, slotA, out);
}

// Round 3
// 185.998 us; speedup vs baseline: 1.4754x; 1.0241x over previous
//
#include <hip/hip_runtime.h>
#include <hip/hip_bf16.h>
#include <cstdint>

#define T_TOK 1024
#define H_DIM 1024
#define I_DIM 512
#define E_NUM 16
#define TOPK  4

typedef __bf16 bf16;
typedef __bf16 bf16x8 __attribute__((ext_vector_type(8)));
typedef float  f32x4  __attribute__((ext_vector_type(4)));

#define GLOAD16(g, l)                                                                   \
  __builtin_amdgcn_global_load_lds((const __attribute__((address_space(1))) void*)(g),  \
                                   (__attribute__((address_space(3))) void*)(l), 16, 0, 0)

// ---------------- init: zero out, reset counts, build shared-expert list ----------------
__global__ void init_kernel(float* __restrict__ out, int* __restrict__ counts,
                            int* __restrict__ tok, float* __restrict__ wt,
                            int* __restrict__ slot) {
  int i = blockIdx.x * 256 + threadIdx.x;   // 0..262143
  f32x4* o4 = (f32x4*)out;                  // 1M floats = 262144 float4
  o4[i] = f32x4{0.f, 0.f, 0.f, 0.f};
  if (i < 32) counts[i] = (i == E_NUM) ? T_TOK : 0;
  if (i < T_TOK) {
    tok [E_NUM * T_TOK + i] = i;
    wt  [E_NUM * T_TOK + i] = 1.0f;
    slot[E_NUM * T_TOK + i] = T_TOK * TOPK + i;
  }
}

// ---------------- convert x fp32 -> bf16 ----------------
__global__ void convx_kernel(const float* __restrict__ x, bf16* __restrict__ xb) {
  int i = blockIdx.x * 256 + threadIdx.x;   // 1M/8 = 131072 threads
  float4 f0 = ((const float4*)x)[i * 2];
  float4 f1 = ((const float4*)x)[i * 2 + 1];
  bf16x8 p;
  p[0]=(bf16)f0.x; p[1]=(bf16)f0.y; p[2]=(bf16)f0.z; p[3]=(bf16)f0.w;
  p[4]=(bf16)f1.x; p[5]=(bf16)f1.y; p[6]=(bf16)f1.z; p[7]=(bf16)f1.w;
  ((bf16x8*)xb)[i] = p;
}

// ---------------- transpose+convert: src fp32 [K][N] -> dst bf16 [N][K], per-mat z ----------------
__global__ void transpose_conv_kernel(const float* __restrict__ src, bf16* __restrict__ dst,
                                      int K, int N) {
  const float* s = src + (size_t)blockIdx.z * K * N;
  bf16* d = dst + (size_t)blockIdx.z * K * N;
  int n = blockIdx.x * 64 + (threadIdx.x & 63);
  int k = blockIdx.y * 32 + (threadIdx.x >> 6) * 8;
  bf16x8 p;
#pragma unroll
  for (int j = 0; j < 8; ++j) p[j] = (bf16)s[(size_t)(k + j) * N + n];
  *(bf16x8*)(d + (size_t)n * K + k) = p;
}

// ---------------- router: ILP-friendly, one wave per token ----------------
// Per-lane partials for all 16 experts, ONE interleaved butterfly (96 independent
// shuffles), then sigmoid + top-4 fully in-register per lane; lane 0 commits.
__global__ void router_kernel(const float* __restrict__ x, const float* __restrict__ gw,
                              int* __restrict__ counts, int* __restrict__ tok,
                              float* __restrict__ wt, int* __restrict__ slot) {
  const int wave = threadIdx.x >> 6, lane = threadIdx.x & 63;
  const int t = blockIdx.x * 4 + wave;
  const float4* xr = (const float4*)(x + (size_t)t * H_DIM);

  float4 xv[4];
#pragma unroll
  for (int j = 0; j < 4; ++j) xv[j] = xr[lane + 64 * j];

  float p[E_NUM];
#pragma unroll
  for (int e = 0; e < E_NUM; ++e) {
    const float4* gr = (const float4*)(gw + (size_t)e * H_DIM);
    float s = 0.f;
#pragma unroll
    for (int j = 0; j < 4; ++j) {
      float4 g = gr[lane + 64 * j];
      s += xv[j].x * g.x + xv[j].y * g.y + xv[j].z * g.z + xv[j].w * g.w;
    }
    p[e] = s;
  }
  // interleaved butterfly: all 16 experts reduced simultaneously (pipelined shuffles)
#pragma unroll
  for (int off = 32; off > 0; off >>= 1) {
#pragma unroll
    for (int e = 0; e < E_NUM; ++e) p[e] += __shfl_xor(p[e], off);
  }
  // sigmoid + in-register top-4 (every lane redundantly; no divergence)
  float rem[E_NUM];
#pragma unroll
  for (int e = 0; e < E_NUM; ++e) rem[e] = 1.f / (1.f + __expf(-p[e]));
  float vals[TOPK]; int idx[TOPK];
#pragma unroll
  for (int k = 0; k < TOPK; ++k) {
    float m = rem[0]; int mi = 0;
#pragma unroll
    for (int e = 1; e < E_NUM; ++e) {
      if (rem[e] > m) { m = rem[e]; mi = e; }
    }
    vals[k] = m; idx[k] = mi;
#pragma unroll
    for (int e = 0; e < E_NUM; ++e) rem[e] = (e == mi) ? -1e30f : rem[e];
  }
  if (lane == 0) {
    float inv = 1.f / (vals[0] + vals[1] + vals[2] + vals[3]);
#pragma unroll
    for (int k = 0; k < TOPK; ++k) {
      int e = idx[k];
      int pos = atomicAdd(&counts[e], 1);
      tok [e * T_TOK + pos] = t;
      wt  [e * T_TOK + pos] = vals[k] * inv;
      slot[e * T_TOK + pos] = t * TOPK + k;
    }
  }
}

// ---------------- GEMM1: gathered Xb [cnt,1024] @ WguT -> swiglu -> h bf16 ----------------
// BM=64 tokens, BN=128 h-cols (128 gate rows + 128 up rows of W^T), BK=32.
__global__ __launch_bounds__(256, 2)
void gemm1_kernel(const bf16* __restrict__ xb, const bf16* __restrict__ wguT,
                  const bf16* __restrict__ sguT, const int* __restrict__ counts,
                  const int* __restrict__ tok, const int* __restrict__ slot,
                  bf16* __restrict__ hbuf) {
  const int e   = blockIdx.z;
  const int cnt = counts[e];
  const int rt  = blockIdx.y;
  if (rt * 64 >= cnt) return;
  const int nb = blockIdx.x * 128;  // h col base within I=512
  const bf16* BT = (e < E_NUM) ? (wguT + (size_t)e * (2 * I_DIM) * H_DIM) : sguT;

  __shared__ __align__(16) bf16 sA[64 * 32];    // [row][k]
  __shared__ __align__(16) bf16 sG[128 * 32];   // [gate col][k]
  __shared__ __align__(16) bf16 sU[128 * 32];   // [up col][k]

  const int tid = threadIdx.x, wave = tid >> 6, lane = tid & 63;
  const int wr = wave >> 1, wc = wave & 1;      // 2x2 wave grid over 64x128
  const int fr = lane & 15, kg = lane >> 4;
  const int lr = lane >> 2, lk = (lane & 3) * 8;  // staging: row-within-16, k-elem offset

  // staging source pointers (per lane); LDS dests (wave-uniform)
  int ar = rt * 64 + wave * 16 + lr;
  int arc = ar < cnt ? ar : cnt - 1;
  const bf16* aS  = xb + (size_t)tok[e * T_TOK + arc] * H_DIM + lk;
  const bf16* gS0 = BT + (size_t)(nb + wave * 32 + lr) * H_DIM + lk;
  const bf16* gS1 = gS0 + (size_t)16 * H_DIM;
  const bf16* uS0 = BT + (size_t)(I_DIM + nb + wave * 32 + lr) * H_DIM + lk;
  const bf16* uS1 = uS0 + (size_t)16 * H_DIM;
  bf16* aL  = sA + wave * 512;   // 16 rows * 32 k
  bf16* gL0 = sG + wave * 1024;  // 32 rows per wave, 2 instrs
  bf16* gL1 = gL0 + 512;
  bf16* uL0 = sU + wave * 1024;
  bf16* uL1 = uL0 + 512;

  f32x4 accg[2][4], accu[2][4];
#pragma unroll
  for (int i = 0; i < 2; ++i)
#pragma unroll
    for (int j = 0; j < 4; ++j) { accg[i][j] = f32x4{0,0,0,0}; accu[i][j] = f32x4{0,0,0,0}; }

  for (int k0 = 0; k0 < H_DIM; k0 += 32) {
    GLOAD16(aS  + k0, aL);
    GLOAD16(gS0 + k0, gL0);
    GLOAD16(gS1 + k0, gL1);
    GLOAD16(uS0 + k0, uL0);
    GLOAD16(uS1 + k0, uL1);
    __syncthreads();
    bf16x8 a0 = *(const bf16x8*)(sA + (wr * 32      + fr) * 32 + kg * 8);
    bf16x8 a1 = *(const bf16x8*)(sA + (wr * 32 + 16 + fr) * 32 + kg * 8);
    bf16x8 bg[4], bu[4];
#pragma unroll
    for (int ni = 0; ni < 4; ++ni) {
      bg[ni] = *(const bf16x8*)(sG + (wc * 64 + ni * 16 + fr) * 32 + kg * 8);
      bu[ni] = *(const bf16x8*)(sU + (wc * 64 + ni * 16 + fr) * 32 + kg * 8);
    }
#pragma unroll
    for (int ni = 0; ni < 4; ++ni) {
      accg[0][ni] = __builtin_amdgcn_mfma_f32_16x16x32_bf16(a0, bg[ni], accg[0][ni], 0, 0, 0);
      accg[1][ni] = __builtin_amdgcn_mfma_f32_16x16x32_bf16(a1, bg[ni], accg[1][ni], 0, 0, 0);
      accu[0][ni] = __builtin_amdgcn_mfma_f32_16x16x32_bf16(a0, bu[ni], accu[0][ni], 0, 0, 0);
      accu[1][ni] = __builtin_amdgcn_mfma_f32_16x16x32_bf16(a1, bu[ni], accu[1][ni], 0, 0, 0);
    }
    __syncthreads();
  }

  // epilogue: swiglu, scatter-store h[slot][col] as bf16
#pragma unroll
  for (int mi = 0; mi < 2; ++mi) {
#pragma unroll
    for (int j = 0; j < 4; ++j) {
      int grow = rt * 64 + wr * 32 + mi * 16 + kg * 4 + j;
      if (grow < cnt) {
        bf16* hr = hbuf + (size_t)slot[e * T_TOK + grow] * I_DIM;
#pragma unroll
        for (int ni = 0; ni < 4; ++ni) {
          float g = accg[mi][ni][j], u = accu[mi][ni][j];
          float h = (g / (1.f + __expf(-g))) * u;
          hr[nb + wc * 64 + ni * 16 + fr] = (bf16)h;
        }
      }
    }
  }
}

// ---------------- GEMM2: gathered h [cnt,512] @ WdT -> weighted atomicAdd into out ----------------
// BM=64, BN=128, BK=32.
__global__ __launch_bounds__(256, 2)
void gemm2_kernel(const bf16* __restrict__ hbuf, const bf16* __restrict__ wdT,
                  const bf16* __restrict__ sdT, const int* __restrict__ counts,
                  const int* __restrict__ tok, const float* __restrict__ wt,
                  const int* __restrict__ slot, float* __restrict__ out) {
  const int e   = blockIdx.z;
  const int cnt = counts[e];
  const int rt  = blockIdx.y;
  if (rt * 64 >= cnt) return;
  const int nb = blockIdx.x * 128;  // out col base within H=1024
  const bf16* BT = (e < E_NUM) ? (wdT + (size_t)e * H_DIM * I_DIM) : sdT;  // [H][I]

  __shared__ __align__(16) bf16 sA[64 * 32];
  __shared__ __align__(16) bf16 sB[128 * 32];

  const int tid = threadIdx.x, wave = tid >> 6, lane = tid & 63;
  const int wr = wave >> 1, wc = wave & 1;
  const int fr = lane & 15, kg = lane >> 4;
  const int lr = lane >> 2, lk = (lane & 3) * 8;

  int ar = rt * 64 + wave * 16 + lr;
  int arc = ar < cnt ? ar : cnt - 1;
  const bf16* aS  = hbuf + (size_t)slot[e * T_TOK + arc] * I_DIM + lk;
  const bf16* bS0 = BT + (size_t)(nb + wave * 32 + lr) * I_DIM + lk;
  const bf16* bS1 = bS0 + (size_t)16 * I_DIM;
  bf16* aL  = sA + wave * 512;
  bf16* bL0 = sB + wave * 1024;
  bf16* bL1 = bL0 + 512;

  f32x4 acc[2][4];
#pragma unroll
  for (int i = 0; i < 2; ++i)
#pragma unroll
    for (int j = 0; j < 4; ++j) acc[i][j] = f32x4{0,0,0,0};

  for (int k0 = 0; k0 < I_DIM; k0 += 32) {
    GLOAD16(aS  + k0, aL);
    GLOAD16(bS0 + k0, bL0);
    GLOAD16(bS1 + k0, bL1);
    __syncthreads();
    bf16x8 a0 = *(const bf16x8*)(sA + (wr * 32      + fr) * 32 + kg * 8);
    bf16x8 a1 = *(const bf16x8*)(sA + (wr * 32 + 16 + fr) * 32 + kg * 8);
    bf16x8 b[4];
#pragma unroll
    for (int ni = 0; ni < 4; ++ni)
      b[ni] = *(const bf16x8*)(sB + (wc * 64 + ni * 16 + fr) * 32 + kg * 8);
#pragma unroll
    for (int ni = 0; ni < 4; ++ni) {
      acc[0][ni] = __builtin_amdgcn_mfma_f32_16x16x32_bf16(a0, b[ni], acc[0][ni], 0, 0, 0);
      acc[1][ni] = __builtin_amdgcn_mfma_f32_16x16x32_bf16(a1, b[ni], acc[1][ni], 0, 0, 0);
    }
    __syncthreads();
  }

#pragma unroll
  for (int mi = 0; mi < 2; ++mi) {
#pragma unroll
    for (int j = 0; j < 4; ++j) {
      int grow = rt * 64 + wr * 32 + mi * 16 + kg * 4 + j;
      if (grow < cnt) {
        int   t = tok[e * T_TOK + grow];
        float w = wt [e * T_TOK + grow];
        float* orow = out + (size_t)t * H_DIM + nb + wc * 64 + fr;
#pragma unroll
        for (int ni = 0; ni < 4; ++ni)
          atomicAdd(orow + ni * 16, w * acc[mi][ni][j]);
      }
    }
  }
}

extern "C" void kernel_launch(void* const* d_in, const int* in_sizes, int n_in,
                              void* d_out, int out_size, void* d_ws, size_t ws_size,
                              hipStream_t stream) {
  const float* x   = (const float*)d_in[0];
  const float* gw  = (const float*)d_in[1];
  const float* wgu = (const float*)d_in[2];
  const float* wd  = (const float*)d_in[3];
  const float* sgu = (const float*)d_in[4];
  const float* sd  = (const float*)d_in[5];
  float* out = (float*)d_out;

  char* ws = (char*)d_ws;
  int*   counts = (int*)  (ws);
  int*   tok    = (int*)  (ws + 1024);
  float* wtA    = (float*)(ws + 70656);
  int*   slotA  = (int*)  (ws + 140288);
  bf16*  xb     = (bf16*) (ws + 212992);               // 2 MB
  bf16*  hbuf   = (bf16*) (ws + 2310144);              // 5.25 MB
  bf16*  wguT   = (bf16*) (ws + 7553024);              // 32 MB  [E][2I][H]
  bf16*  wdT    = (bf16*) (ws + 41107456);             // 16 MB  [E][H][I]
  bf16*  sguT   = (bf16*) (ws + 57884672);             // 2 MB   [2I][H]
  bf16*  sdT    = (bf16*) (ws + 59981824);             // 1 MB   [H][I]
  // total ws use ~61.0 MB

  init_kernel<<<1024, 256, 0, stream>>>(out, counts, tok, wtA, slotA);
  convx_kernel<<<512, 256, 0, stream>>>(x, xb);
  transpose_conv_kernel<<<dim3(16, 32, E_NUM), 256, 0, stream>>>(wgu, wguT, H_DIM, 2 * I_DIM);
  transpose_conv_kernel<<<dim3(16, 16, E_NUM), 256, 0, stream>>>(wd,  wdT,  I_DIM, H_DIM);
  transpose_conv_kernel<<<dim3(16, 32, 1),     256, 0, stream>>>(sgu, sguT, H_DIM, 2 * I_DIM);
  transpose_conv_kernel<<<dim3(16, 16, 1),     256, 0, stream>>>(sd,  sdT,  I_DIM, H_DIM);
  router_kernel<<<T_TOK / 4, 256, 0, stream>>>(x, gw, counts, tok, wtA, slotA);
  gemm1_kernel<<<dim3(4, 16, 17), 256, 0, stream>>>(xb, wguT, sguT, counts, tok, slotA, hbuf);
  gemm2_kernel<<<dim3(8, 16, 17), 256, 0, stream>>>(hbuf, wdT, sdT, counts, tok, wtA, slotA, out);
}

// Round 4
// 142.694 us; speedup vs baseline: 1.9232x; 1.3035x over previous
//
#include <hip/hip_runtime.h>
#include <hip/hip_bf16.h>
#include <cstdint>

#define T_TOK 1024
#define H_DIM 1024
#define I_DIM 512
#define E_NUM 16
#define TOPK  4

typedef __bf16 bf16;
typedef __bf16 bf16x8 __attribute__((ext_vector_type(8)));
typedef float  f32x4  __attribute__((ext_vector_type(4)));

#define GLOAD16(g, l)                                                                   \
  __builtin_amdgcn_global_load_lds((const __attribute__((address_space(1))) void*)(g),  \
                                   (__attribute__((address_space(3))) void*)(l), 16, 0, 0)

// ---------------- init: zero out, build shared-expert list ----------------
__global__ void init_kernel(float* __restrict__ out, int* __restrict__ counts,
                            int* __restrict__ tok, float* __restrict__ wt,
                            int* __restrict__ slot) {
  int i = blockIdx.x * 256 + threadIdx.x;   // 0..262143
  f32x4* o4 = (f32x4*)out;                  // 1M floats = 262144 float4
  o4[i] = f32x4{0.f, 0.f, 0.f, 0.f};
  if (i == 0) counts[E_NUM] = T_TOK;
  if (i < T_TOK) {
    tok [E_NUM * T_TOK + i] = i;
    wt  [E_NUM * T_TOK + i] = 1.0f;
    slot[E_NUM * T_TOK + i] = T_TOK * TOPK + i;
  }
}

// ---------------- convert x fp32 -> bf16 ----------------
__global__ void convx_kernel(const float* __restrict__ x, bf16* __restrict__ xb) {
  int i = blockIdx.x * 256 + threadIdx.x;   // 131072 threads
  float4 f0 = ((const float4*)x)[i * 2];
  float4 f1 = ((const float4*)x)[i * 2 + 1];
  bf16x8 p;
  p[0]=(bf16)f0.x; p[1]=(bf16)f0.y; p[2]=(bf16)f0.z; p[3]=(bf16)f0.w;
  p[4]=(bf16)f1.x; p[5]=(bf16)f1.y; p[6]=(bf16)f1.z; p[7]=(bf16)f1.w;
  ((bf16x8*)xb)[i] = p;
}

// ---------------- LDS-tiled transpose+convert: src fp32 [K][N] -> dst bf16 [N][K] ----------------
// 64x64 tile per block. Coalesced fp32 reads; scalar ds_write_b16 transpose;
// coalesced 128B-row bf16 writes.
__global__ void transpose_conv_kernel(const float* __restrict__ src, bf16* __restrict__ dst,
                                      int K, int N) {
  __shared__ __align__(16) bf16 tile[64 * 72];  // [n][k], stride 72 elem = 144B
  const int tid = threadIdx.x;
  const size_t mat = (size_t)blockIdx.z * K * N;
  const int kb = blockIdx.y * 64, nb = blockIdx.x * 64;

  // phase 1: read 64k x 64n fp32, write transposed bf16 into LDS
  {
    const int k = tid >> 2, nq = (tid & 3) * 16;
    const float4* s = (const float4*)(src + mat + (size_t)(kb + k) * N + nb + nq);
    float4 f[4];
#pragma unroll
    for (int q = 0; q < 4; ++q) f[q] = s[q];
    const float* fs = (const float*)f;
#pragma unroll
    for (int j = 0; j < 16; ++j) tile[(nq + j) * 72 + k] = (bf16)fs[j];
  }
  __syncthreads();
  // phase 2: write rows of dst (bf16 [N][K]) coalesced
  {
    const int n = tid >> 2, kq = (tid & 3) * 16;
    bf16x8 p0 = *(const bf16x8*)(tile + n * 72 + kq);
    bf16x8 p1 = *(const bf16x8*)(tile + n * 72 + kq + 8);
    bf16* d = dst + mat + (size_t)(nb + n) * K + kb + kq;
    *(bf16x8*)d = p0;
    *(bf16x8*)(d + 8) = p1;
  }
}

// ---------------- router phase 1: scores + in-register top-4, dense writes ----------------
__global__ void router_score_kernel(const float* __restrict__ x, const float* __restrict__ gw,
                                    int* __restrict__ topk_e, float* __restrict__ topk_w) {
  const int wave = threadIdx.x >> 6, lane = threadIdx.x & 63;
  const int t = blockIdx.x * 4 + wave;
  const float4* xr = (const float4*)(x + (size_t)t * H_DIM);

  float4 xv[4];
#pragma unroll
  for (int j = 0; j < 4; ++j) xv[j] = xr[lane + 64 * j];

  float p[E_NUM];
#pragma unroll
  for (int e = 0; e < E_NUM; ++e) {
    const float4* gr = (const float4*)(gw + (size_t)e * H_DIM);
    float s = 0.f;
#pragma unroll
    for (int j = 0; j < 4; ++j) {
      float4 g = gr[lane + 64 * j];
      s += xv[j].x * g.x + xv[j].y * g.y + xv[j].z * g.z + xv[j].w * g.w;
    }
    p[e] = s;
  }
#pragma unroll
  for (int off = 32; off > 0; off >>= 1) {
#pragma unroll
    for (int e = 0; e < E_NUM; ++e) p[e] += __shfl_xor(p[e], off);
  }
  float rem[E_NUM];
#pragma unroll
  for (int e = 0; e < E_NUM; ++e) rem[e] = 1.f / (1.f + __expf(-p[e]));
  float vals[TOPK]; int idx[TOPK];
#pragma unroll
  for (int k = 0; k < TOPK; ++k) {
    float m = rem[0]; int mi = 0;
#pragma unroll
    for (int e = 1; e < E_NUM; ++e) {
      if (rem[e] > m) { m = rem[e]; mi = e; }
    }
    vals[k] = m; idx[k] = mi;
#pragma unroll
    for (int e = 0; e < E_NUM; ++e) rem[e] = (e == mi) ? -1e30f : rem[e];
  }
  if (lane == 0) {
    float inv = 1.f / (vals[0] + vals[1] + vals[2] + vals[3]);
    int4 ids; ids.x = idx[0]; ids.y = idx[1]; ids.z = idx[2]; ids.w = idx[3];
    float4 w4; w4.x = vals[0]*inv; w4.y = vals[1]*inv; w4.z = vals[2]*inv; w4.w = vals[3]*inv;
    ((int4*)topk_e)[t] = ids;
    ((float4*)topk_w)[t] = w4;
  }
}

// ---------------- router phase 2: per-expert list build via ballot prefix (no atomics) ----------------
__global__ void router_build_kernel(const int* __restrict__ topk_e, const float* __restrict__ topk_w,
                                    int* __restrict__ counts, int* __restrict__ tok,
                                    float* __restrict__ wt, int* __restrict__ slot) {
  const int e = blockIdx.x;  // 0..15
  const int tid = threadIdx.x, wave = tid >> 6, lane = tid & 63;
  __shared__ int wsum[4];
  int base = 0;
  for (int r = 0; r < 4; ++r) {
    int t = r * 256 + tid;
    int4 ids = ((const int4*)topk_e)[t];
    int match = -1;
    if (ids.x == e) match = 0;
    if (ids.y == e) match = 1;
    if (ids.z == e) match = 2;
    if (ids.w == e) match = 3;
    unsigned long long b = __ballot(match >= 0);
    int prefix = __popcll(b & ((1ull << lane) - 1ull));
    if (lane == 0) wsum[wave] = __popcll(b);
    __syncthreads();
    int wbase = 0;
#pragma unroll
    for (int wv = 0; wv < 4; ++wv) wbase += (wv < wave) ? wsum[wv] : 0;
    int total = wsum[0] + wsum[1] + wsum[2] + wsum[3];
    if (match >= 0) {
      int pos = base + wbase + prefix;
      tok [e * T_TOK + pos] = t;
      wt  [e * T_TOK + pos] = topk_w[t * 4 + match];
      slot[e * T_TOK + pos] = t * 4 + match;
    }
    base += total;
    __syncthreads();
  }
  if (tid == 0) counts[e] = base;
}

// ---------------- GEMM1: gathered Xb [cnt,1024] @ WguT -> swiglu -> h bf16 ----------------
__global__ __launch_bounds__(256, 2)
void gemm1_kernel(const bf16* __restrict__ xb, const bf16* __restrict__ wguT,
                  const bf16* __restrict__ sguT, const int* __restrict__ counts,
                  const int* __restrict__ tok, const int* __restrict__ slot,
                  bf16* __restrict__ hbuf) {
  const int e   = blockIdx.z;
  const int cnt = counts[e];
  const int rt  = blockIdx.y;
  if (rt * 64 >= cnt) return;
  const int nb = blockIdx.x * 128;
  const bf16* BT = (e < E_NUM) ? (wguT + (size_t)e * (2 * I_DIM) * H_DIM) : sguT;

  __shared__ __align__(16) bf16 sA[64 * 32];
  __shared__ __align__(16) bf16 sG[128 * 32];
  __shared__ __align__(16) bf16 sU[128 * 32];

  const int tid = threadIdx.x, wave = tid >> 6, lane = tid & 63;
  const int wr = wave >> 1, wc = wave & 1;
  const int fr = lane & 15, kg = lane >> 4;
  const int lr = lane >> 2, lk = (lane & 3) * 8;

  int ar = rt * 64 + wave * 16 + lr;
  int arc = ar < cnt ? ar : cnt - 1;
  const bf16* aS  = xb + (size_t)tok[e * T_TOK + arc] * H_DIM + lk;
  const bf16* gS0 = BT + (size_t)(nb + wave * 32 + lr) * H_DIM + lk;
  const bf16* gS1 = gS0 + (size_t)16 * H_DIM;
  const bf16* uS0 = BT + (size_t)(I_DIM + nb + wave * 32 + lr) * H_DIM + lk;
  const bf16* uS1 = uS0 + (size_t)16 * H_DIM;
  bf16* aL  = sA + wave * 512;
  bf16* gL0 = sG + wave * 1024;
  bf16* gL1 = gL0 + 512;
  bf16* uL0 = sU + wave * 1024;
  bf16* uL1 = uL0 + 512;

  f32x4 accg[2][4], accu[2][4];
#pragma unroll
  for (int i = 0; i < 2; ++i)
#pragma unroll
    for (int j = 0; j < 4; ++j) { accg[i][j] = f32x4{0,0,0,0}; accu[i][j] = f32x4{0,0,0,0}; }

  for (int k0 = 0; k0 < H_DIM; k0 += 32) {
    GLOAD16(aS  + k0, aL);
    GLOAD16(gS0 + k0, gL0);
    GLOAD16(gS1 + k0, gL1);
    GLOAD16(uS0 + k0, uL0);
    GLOAD16(uS1 + k0, uL1);
    __syncthreads();
    bf16x8 a0 = *(const bf16x8*)(sA + (wr * 32      + fr) * 32 + kg * 8);
    bf16x8 a1 = *(const bf16x8*)(sA + (wr * 32 + 16 + fr) * 32 + kg * 8);
    bf16x8 bg[4], bu[4];
#pragma unroll
    for (int ni = 0; ni < 4; ++ni) {
      bg[ni] = *(const bf16x8*)(sG + (wc * 64 + ni * 16 + fr) * 32 + kg * 8);
      bu[ni] = *(const bf16x8*)(sU + (wc * 64 + ni * 16 + fr) * 32 + kg * 8);
    }
#pragma unroll
    for (int ni = 0; ni < 4; ++ni) {
      accg[0][ni] = __builtin_amdgcn_mfma_f32_16x16x32_bf16(a0, bg[ni], accg[0][ni], 0, 0, 0);
      accg[1][ni] = __builtin_amdgcn_mfma_f32_16x16x32_bf16(a1, bg[ni], accg[1][ni], 0, 0, 0);
      accu[0][ni] = __builtin_amdgcn_mfma_f32_16x16x32_bf16(a0, bu[ni], accu[0][ni], 0, 0, 0);
      accu[1][ni] = __builtin_amdgcn_mfma_f32_16x16x32_bf16(a1, bu[ni], accu[1][ni], 0, 0, 0);
    }
    __syncthreads();
  }

#pragma unroll
  for (int mi = 0; mi < 2; ++mi) {
#pragma unroll
    for (int j = 0; j < 4; ++j) {
      int grow = rt * 64 + wr * 32 + mi * 16 + kg * 4 + j;
      if (grow < cnt) {
        bf16* hr = hbuf + (size_t)slot[e * T_TOK + grow] * I_DIM;
#pragma unroll
        for (int ni = 0; ni < 4; ++ni) {
          float g = accg[mi][ni][j], u = accu[mi][ni][j];
          float h = (g / (1.f + __expf(-g))) * u;
          hr[nb + wc * 64 + ni * 16 + fr] = (bf16)h;
        }
      }
    }
  }
}

// ---------------- GEMM2: gathered h [cnt,512] @ WdT -> weighted atomicAdd into out ----------------
__global__ __launch_bounds__(256, 2)
void gemm2_kernel(const bf16* __restrict__ hbuf, const bf16* __restrict__ wdT,
                  const bf16* __restrict__ sdT, const int* __restrict__ counts,
                  const int* __restrict__ tok, const float* __restrict__ wt,
                  const int* __restrict__ slot, float* __restrict__ out) {
  const int e   = blockIdx.z;
  const int cnt = counts[e];
  const int rt  = blockIdx.y;
  if (rt * 64 >= cnt) return;
  const int nb = blockIdx.x * 128;
  const bf16* BT = (e < E_NUM) ? (wdT + (size_t)e * H_DIM * I_DIM) : sdT;

  __shared__ __align__(16) bf16 sA[64 * 32];
  __shared__ __align__(16) bf16 sB[128 * 32];

  const int tid = threadIdx.x, wave = tid >> 6, lane = tid & 63;
  const int wr = wave >> 1, wc = wave & 1;
  const int fr = lane & 15, kg = lane >> 4;
  const int lr = lane >> 2, lk = (lane & 3) * 8;

  int ar = rt * 64 + wave * 16 + lr;
  int arc = ar < cnt ? ar : cnt - 1;
  const bf16* aS  = hbuf + (size_t)slot[e * T_TOK + arc] * I_DIM + lk;
  const bf16* bS0 = BT + (size_t)(nb + wave * 32 + lr) * I_DIM + lk;
  const bf16* bS1 = bS0 + (size_t)16 * I_DIM;
  bf16* aL  = sA + wave * 512;
  bf16* bL0 = sB + wave * 1024;
  bf16* bL1 = bL0 + 512;

  f32x4 acc[2][4];
#pragma unroll
  for (int i = 0; i < 2; ++i)
#pragma unroll
    for (int j = 0; j < 4; ++j) acc[i][j] = f32x4{0,0,0,0};

  for (int k0 = 0; k0 < I_DIM; k0 += 32) {
    GLOAD16(aS  + k0, aL);
    GLOAD16(bS0 + k0, bL0);
    GLOAD16(bS1 + k0, bL1);
    __syncthreads();
    bf16x8 a0 = *(const bf16x8*)(sA + (wr * 32      + fr) * 32 + kg * 8);
    bf16x8 a1 = *(const bf16x8*)(sA + (wr * 32 + 16 + fr) * 32 + kg * 8);
    bf16x8 b[4];
#pragma unroll
    for (int ni = 0; ni < 4; ++ni)
      b[ni] = *(const bf16x8*)(sB + (wc * 64 + ni * 16 + fr) * 32 + kg * 8);
#pragma unroll
    for (int ni = 0; ni < 4; ++ni) {
      acc[0][ni] = __builtin_amdgcn_mfma_f32_16x16x32_bf16(a0, b[ni], acc[0][ni], 0, 0, 0);
      acc[1][ni] = __builtin_amdgcn_mfma_f32_16x16x32_bf16(a1, b[ni], acc[1][ni], 0, 0, 0);
    }
    __syncthreads();
  }

#pragma unroll
  for (int mi = 0; mi < 2; ++mi) {
#pragma unroll
    for (int j = 0; j < 4; ++j) {
      int grow = rt * 64 + wr * 32 + mi * 16 + kg * 4 + j;
      if (grow < cnt) {
        int   t = tok[e * T_TOK + grow];
        float w = wt [e * T_TOK + grow];
        float* orow = out + (size_t)t * H_DIM + nb + wc * 64 + fr;
#pragma unroll
        for (int ni = 0; ni < 4; ++ni)
          atomicAdd(orow + ni * 16, w * acc[mi][ni][j]);
      }
    }
  }
}

extern "C" void kernel_launch(void* const* d_in, const int* in_sizes, int n_in,
                              void* d_out, int out_size, void* d_ws, size_t ws_size,
                              hipStream_t stream) {
  const float* x   = (const float*)d_in[0];
  const float* gw  = (const float*)d_in[1];
  const float* wgu = (const float*)d_in[2];
  const float* wd  = (const float*)d_in[3];
  const float* sgu = (const float*)d_in[4];
  const float* sd  = (const float*)d_in[5];
  float* out = (float*)d_out;

  char* ws = (char*)d_ws;
  int*   counts = (int*)  (ws);                 // 1 KB
  int*   tok    = (int*)  (ws + 1024);          // 68 KB
  float* wtA    = (float*)(ws + 70656);         // 68 KB
  int*   slotA  = (int*)  (ws + 140288);        // 68 KB
  int*   topk_e = (int*)  (ws + 209920);        // 16 KB
  float* topk_w = (float*)(ws + 226304);        // 16 KB
  bf16*  xb     = (bf16*) (ws + 245760);        // 2 MB
  bf16*  hbuf   = (bf16*) (ws + 2342912);       // 5.25 MB
  bf16*  wguT   = (bf16*) (ws + 7585792);       // 32 MB  [E][2I][H]
  bf16*  wdT    = (bf16*) (ws + 41140224);      // 16 MB  [E][H][I]
  bf16*  sguT   = (bf16*) (ws + 57917440);      // 2 MB   [2I][H]
  bf16*  sdT    = (bf16*) (ws + 60014592);      // 1 MB   [H][I]
  // total ~61.1 MB

  init_kernel<<<1024, 256, 0, stream>>>(out, counts, tok, wtA, slotA);
  convx_kernel<<<512, 256, 0, stream>>>(x, xb);
  transpose_conv_kernel<<<dim3(16, 16, E_NUM), 256, 0, stream>>>(wgu, wguT, H_DIM, 2 * I_DIM);
  transpose_conv_kernel<<<dim3(16,  8, E_NUM), 256, 0, stream>>>(wd,  wdT,  I_DIM, H_DIM);
  transpose_conv_kernel<<<dim3(16, 16, 1),     256, 0, stream>>>(sgu, sguT, H_DIM, 2 * I_DIM);
  transpose_conv_kernel<<<dim3(16,  8, 1),     256, 0, stream>>>(sd,  sdT,  I_DIM, H_DIM);
  router_score_kernel<<<T_TOK / 4, 256, 0, stream>>>(x, gw, topk_e, topk_w);
  router_build_kernel<<<E_NUM, 256, 0, stream>>>(topk_e, topk_w, counts, tok, wtA, slotA);
  gemm1_kernel<<<dim3(4, 16, 17), 256, 0, stream>>>(xb, wguT, sguT, counts, tok, slotA, hbuf);
  gemm2_kernel<<<dim3(8, 16, 17), 256, 0, stream>>>(hbuf, wdT, sdT, counts, tok, wtA, slotA, out);
}

// Round 5
// 128.015 us; speedup vs baseline: 2.1437x; 1.1147x over previous
//
#include <hip/hip_runtime.h>
#include <hip/hip_bf16.h>
#include <cstdint>

#define T_TOK 1024
#define H_DIM 1024
#define I_DIM 512
#define E_NUM 16
#define TOPK  4

typedef __bf16 bf16;
typedef __bf16 bf16x8 __attribute__((ext_vector_type(8)));
typedef float  f32x4  __attribute__((ext_vector_type(4)));

#define GLOAD16(g, l)                                                                   \
  __builtin_amdgcn_global_load_lds((const __attribute__((address_space(1))) void*)(g),  \
                                   (__attribute__((address_space(3))) void*)(l), 16, 0, 0)

// ---------------- init: zero out, build shared-expert list ----------------
__global__ void init_kernel(float* __restrict__ out, int* __restrict__ counts,
                            int* __restrict__ tok, float* __restrict__ wt,
                            int* __restrict__ slot) {
  int i = blockIdx.x * 256 + threadIdx.x;   // 0..262143
  f32x4* o4 = (f32x4*)out;                  // 1M floats = 262144 float4
  o4[i] = f32x4{0.f, 0.f, 0.f, 0.f};
  if (i == 0) counts[E_NUM] = T_TOK;
  if (i < T_TOK) {
    tok [E_NUM * T_TOK + i] = i;
    wt  [E_NUM * T_TOK + i] = 1.0f;
    slot[E_NUM * T_TOK + i] = T_TOK * TOPK + i;
  }
}

// ---------------- convert x fp32 -> bf16 ----------------
__global__ void convx_kernel(const float* __restrict__ x, bf16* __restrict__ xb) {
  int i = blockIdx.x * 256 + threadIdx.x;   // 131072 threads
  float4 f0 = ((const float4*)x)[i * 2];
  float4 f1 = ((const float4*)x)[i * 2 + 1];
  bf16x8 p;
  p[0]=(bf16)f0.x; p[1]=(bf16)f0.y; p[2]=(bf16)f0.z; p[3]=(bf16)f0.w;
  p[4]=(bf16)f1.x; p[5]=(bf16)f1.y; p[6]=(bf16)f1.z; p[7]=(bf16)f1.w;
  ((bf16x8*)xb)[i] = p;
}

// ---------------- LDS-tiled transpose+convert: src fp32 [K][N] -> dst bf16 [N][K] ----------------
__global__ void transpose_conv_kernel(const float* __restrict__ src, bf16* __restrict__ dst,
                                      int K, int N) {
  __shared__ __align__(16) bf16 tile[64 * 72];  // [n][k], stride 72 elem
  const int tid = threadIdx.x;
  const size_t mat = (size_t)blockIdx.z * K * N;
  const int kb = blockIdx.y * 64, nb = blockIdx.x * 64;

  {
    const int k = tid >> 2, nq = (tid & 3) * 16;
    const float4* s = (const float4*)(src + mat + (size_t)(kb + k) * N + nb + nq);
    float4 f[4];
#pragma unroll
    for (int q = 0; q < 4; ++q) f[q] = s[q];
    const float* fs = (const float*)f;
#pragma unroll
    for (int j = 0; j < 16; ++j) tile[(nq + j) * 72 + k] = (bf16)fs[j];
  }
  __syncthreads();
  {
    const int n = tid >> 2, kq = (tid & 3) * 16;
    bf16x8 p0 = *(const bf16x8*)(tile + n * 72 + kq);
    bf16x8 p1 = *(const bf16x8*)(tile + n * 72 + kq + 8);
    bf16* d = dst + mat + (size_t)(nb + n) * K + kb + kq;
    *(bf16x8*)d = p0;
    *(bf16x8*)(d + 8) = p1;
  }
}

// ---------------- router phase 1: scores + in-register top-4, dense writes ----------------
__global__ void router_score_kernel(const float* __restrict__ x, const float* __restrict__ gw,
                                    int* __restrict__ topk_e, float* __restrict__ topk_w) {
  const int wave = threadIdx.x >> 6, lane = threadIdx.x & 63;
  const int t = blockIdx.x * 4 + wave;
  const float4* xr = (const float4*)(x + (size_t)t * H_DIM);

  float4 xv[4];
#pragma unroll
  for (int j = 0; j < 4; ++j) xv[j] = xr[lane + 64 * j];

  float p[E_NUM];
#pragma unroll
  for (int e = 0; e < E_NUM; ++e) {
    const float4* gr = (const float4*)(gw + (size_t)e * H_DIM);
    float s = 0.f;
#pragma unroll
    for (int j = 0; j < 4; ++j) {
      float4 g = gr[lane + 64 * j];
      s += xv[j].x * g.x + xv[j].y * g.y + xv[j].z * g.z + xv[j].w * g.w;
    }
    p[e] = s;
  }
#pragma unroll
  for (int off = 32; off > 0; off >>= 1) {
#pragma unroll
    for (int e = 0; e < E_NUM; ++e) p[e] += __shfl_xor(p[e], off);
  }
  float rem[E_NUM];
#pragma unroll
  for (int e = 0; e < E_NUM; ++e) rem[e] = 1.f / (1.f + __expf(-p[e]));
  float vals[TOPK]; int idx[TOPK];
#pragma unroll
  for (int k = 0; k < TOPK; ++k) {
    float m = rem[0]; int mi = 0;
#pragma unroll
    for (int e = 1; e < E_NUM; ++e) {
      if (rem[e] > m) { m = rem[e]; mi = e; }
    }
    vals[k] = m; idx[k] = mi;
#pragma unroll
    for (int e = 0; e < E_NUM; ++e) rem[e] = (e == mi) ? -1e30f : rem[e];
  }
  if (lane == 0) {
    float inv = 1.f / (vals[0] + vals[1] + vals[2] + vals[3]);
    int4 ids; ids.x = idx[0]; ids.y = idx[1]; ids.z = idx[2]; ids.w = idx[3];
    float4 w4; w4.x = vals[0]*inv; w4.y = vals[1]*inv; w4.z = vals[2]*inv; w4.w = vals[3]*inv;
    ((int4*)topk_e)[t] = ids;
    ((float4*)topk_w)[t] = w4;
  }
}

// ---------------- router phase 2: per-expert list build via ballot prefix (no atomics) ----------------
__global__ void router_build_kernel(const int* __restrict__ topk_e, const float* __restrict__ topk_w,
                                    int* __restrict__ counts, int* __restrict__ tok,
                                    float* __restrict__ wt, int* __restrict__ slot) {
  const int e = blockIdx.x;  // 0..15
  const int tid = threadIdx.x, wave = tid >> 6, lane = tid & 63;
  __shared__ int wsum[4];
  int base = 0;
  for (int r = 0; r < 4; ++r) {
    int t = r * 256 + tid;
    int4 ids = ((const int4*)topk_e)[t];
    int match = -1;
    if (ids.x == e) match = 0;
    if (ids.y == e) match = 1;
    if (ids.z == e) match = 2;
    if (ids.w == e) match = 3;
    unsigned long long b = __ballot(match >= 0);
    int prefix = __popcll(b & ((1ull << lane) - 1ull));
    if (lane == 0) wsum[wave] = __popcll(b);
    __syncthreads();
    int wbase = 0;
#pragma unroll
    for (int wv = 0; wv < 4; ++wv) wbase += (wv < wave) ? wsum[wv] : 0;
    int total = wsum[0] + wsum[1] + wsum[2] + wsum[3];
    if (match >= 0) {
      int pos = base + wbase + prefix;
      tok [e * T_TOK + pos] = t;
      wt  [e * T_TOK + pos] = topk_w[t * 4 + match];
      slot[e * T_TOK + pos] = t * 4 + match;
    }
    base += total;
    __syncthreads();
  }
  if (tid == 0) counts[e] = base;
}

// ---------------- GEMM1: gathered Xb [cnt,1024] @ WguT -> swiglu -> h bf16 ----------------
// BM=64, BN=64 h-cols (64 gate + 64 up rows of W^T), BK=32, double-buffered LDS.
__global__ __launch_bounds__(256, 4)
void gemm1_kernel(const bf16* __restrict__ xb, const bf16* __restrict__ wguT,
                  const bf16* __restrict__ sguT, const int* __restrict__ counts,
                  const int* __restrict__ tok, const int* __restrict__ slot,
                  bf16* __restrict__ hbuf) {
  const int e   = blockIdx.z;
  const int cnt = counts[e];
  const int rt  = blockIdx.y;
  if (rt * 64 >= cnt) return;
  const int nb = blockIdx.x * 64;  // h col base within I=512
  const bf16* BT = (e < E_NUM) ? (wguT + (size_t)e * (2 * I_DIM) * H_DIM) : sguT;

  __shared__ __align__(16) bf16 sA[2][64 * 32];
  __shared__ __align__(16) bf16 sG[2][64 * 32];
  __shared__ __align__(16) bf16 sU[2][64 * 32];

  const int tid = threadIdx.x, wave = tid >> 6, lane = tid & 63;
  const int wr = wave >> 1, wc = wave & 1;      // 2x2 wave grid over 64x64
  const int fr = lane & 15, kg = lane >> 4;
  const int lr = lane >> 2, lk = (lane & 3) * 8;

  int ar = rt * 64 + wave * 16 + lr;
  int arc = ar < cnt ? ar : cnt - 1;
  const bf16* aS = xb + (size_t)tok[e * T_TOK + arc] * H_DIM + lk;
  const bf16* gS = BT + (size_t)(nb + wave * 16 + lr) * H_DIM + lk;
  const bf16* uS = BT + (size_t)(I_DIM + nb + wave * 16 + lr) * H_DIM + lk;
  const int ldsOff = wave * 512;   // 16 rows * 32 k per wave

  f32x4 accg[2][2], accu[2][2];
#pragma unroll
  for (int i = 0; i < 2; ++i)
#pragma unroll
    for (int j = 0; j < 2; ++j) { accg[i][j] = f32x4{0,0,0,0}; accu[i][j] = f32x4{0,0,0,0}; }

  // prologue: stage tile 0 into buf 0
  GLOAD16(aS, sA[0] + ldsOff);
  GLOAD16(gS, sG[0] + ldsOff);
  GLOAD16(uS, sU[0] + ldsOff);
  __syncthreads();

  int cur = 0;
  for (int k0 = 0; k0 < H_DIM; k0 += 32) {
    if (k0 + 32 < H_DIM) {  // prefetch next tile into buf^1 (overlaps MFMA below)
      GLOAD16(aS + k0 + 32, sA[cur ^ 1] + ldsOff);
      GLOAD16(gS + k0 + 32, sG[cur ^ 1] + ldsOff);
      GLOAD16(uS + k0 + 32, sU[cur ^ 1] + ldsOff);
    }
    bf16x8 a0 = *(const bf16x8*)(sA[cur] + (wr * 32      + fr) * 32 + kg * 8);
    bf16x8 a1 = *(const bf16x8*)(sA[cur] + (wr * 32 + 16 + fr) * 32 + kg * 8);
    bf16x8 g0 = *(const bf16x8*)(sG[cur] + (wc * 32      + fr) * 32 + kg * 8);
    bf16x8 g1 = *(const bf16x8*)(sG[cur] + (wc * 32 + 16 + fr) * 32 + kg * 8);
    bf16x8 u0 = *(const bf16x8*)(sU[cur] + (wc * 32      + fr) * 32 + kg * 8);
    bf16x8 u1 = *(const bf16x8*)(sU[cur] + (wc * 32 + 16 + fr) * 32 + kg * 8);
    accg[0][0] = __builtin_amdgcn_mfma_f32_16x16x32_bf16(a0, g0, accg[0][0], 0, 0, 0);
    accg[0][1] = __builtin_amdgcn_mfma_f32_16x16x32_bf16(a0, g1, accg[0][1], 0, 0, 0);
    accg[1][0] = __builtin_amdgcn_mfma_f32_16x16x32_bf16(a1, g0, accg[1][0], 0, 0, 0);
    accg[1][1] = __builtin_amdgcn_mfma_f32_16x16x32_bf16(a1, g1, accg[1][1], 0, 0, 0);
    accu[0][0] = __builtin_amdgcn_mfma_f32_16x16x32_bf16(a0, u0, accu[0][0], 0, 0, 0);
    accu[0][1] = __builtin_amdgcn_mfma_f32_16x16x32_bf16(a0, u1, accu[0][1], 0, 0, 0);
    accu[1][0] = __builtin_amdgcn_mfma_f32_16x16x32_bf16(a1, u0, accu[1][0], 0, 0, 0);
    accu[1][1] = __builtin_amdgcn_mfma_f32_16x16x32_bf16(a1, u1, accu[1][1], 0, 0, 0);
    __syncthreads();   // vmcnt(0)+lgkmcnt(0)+barrier: next buf ready, this buf free
    cur ^= 1;
  }

  // epilogue: swiglu, scatter-store h[slot][col] as bf16
#pragma unroll
  for (int mi = 0; mi < 2; ++mi) {
#pragma unroll
    for (int j = 0; j < 4; ++j) {
      int grow = rt * 64 + wr * 32 + mi * 16 + kg * 4 + j;
      if (grow < cnt) {
        bf16* hr = hbuf + (size_t)slot[e * T_TOK + grow] * I_DIM;
#pragma unroll
        for (int ni = 0; ni < 2; ++ni) {
          float g = accg[mi][ni][j], u = accu[mi][ni][j];
          float h = (g / (1.f + __expf(-g))) * u;
          hr[nb + wc * 32 + ni * 16 + fr] = (bf16)h;
        }
      }
    }
  }
}

// ---------------- GEMM2: gathered h [cnt,512] @ WdT -> weighted atomicAdd into out ----------------
// BM=64, BN=128, BK=32, double-buffered LDS.
__global__ __launch_bounds__(256, 4)
void gemm2_kernel(const bf16* __restrict__ hbuf, const bf16* __restrict__ wdT,
                  const bf16* __restrict__ sdT, const int* __restrict__ counts,
                  const int* __restrict__ tok, const float* __restrict__ wt,
                  const int* __restrict__ slot, float* __restrict__ out) {
  const int e   = blockIdx.z;
  const int cnt = counts[e];
  const int rt  = blockIdx.y;
  if (rt * 64 >= cnt) return;
  const int nb = blockIdx.x * 128;
  const bf16* BT = (e < E_NUM) ? (wdT + (size_t)e * H_DIM * I_DIM) : sdT;

  __shared__ __align__(16) bf16 sA[2][64 * 32];
  __shared__ __align__(16) bf16 sB[2][128 * 32];

  const int tid = threadIdx.x, wave = tid >> 6, lane = tid & 63;
  const int wr = wave >> 1, wc = wave & 1;
  const int fr = lane & 15, kg = lane >> 4;
  const int lr = lane >> 2, lk = (lane & 3) * 8;

  int ar = rt * 64 + wave * 16 + lr;
  int arc = ar < cnt ? ar : cnt - 1;
  const bf16* aS  = hbuf + (size_t)slot[e * T_TOK + arc] * I_DIM + lk;
  const bf16* bS0 = BT + (size_t)(nb + wave * 32 + lr) * I_DIM + lk;
  const bf16* bS1 = bS0 + (size_t)16 * I_DIM;
  const int aOff  = wave * 512;
  const int bOff0 = wave * 1024;
  const int bOff1 = bOff0 + 512;

  f32x4 acc[2][4];
#pragma unroll
  for (int i = 0; i < 2; ++i)
#pragma unroll
    for (int j = 0; j < 4; ++j) acc[i][j] = f32x4{0,0,0,0};

  GLOAD16(aS,  sA[0] + aOff);
  GLOAD16(bS0, sB[0] + bOff0);
  GLOAD16(bS1, sB[0] + bOff1);
  __syncthreads();

  int cur = 0;
  for (int k0 = 0; k0 < I_DIM; k0 += 32) {
    if (k0 + 32 < I_DIM) {
      GLOAD16(aS  + k0 + 32, sA[cur ^ 1] + aOff);
      GLOAD16(bS0 + k0 + 32, sB[cur ^ 1] + bOff0);
      GLOAD16(bS1 + k0 + 32, sB[cur ^ 1] + bOff1);
    }
    bf16x8 a0 = *(const bf16x8*)(sA[cur] + (wr * 32      + fr) * 32 + kg * 8);
    bf16x8 a1 = *(const bf16x8*)(sA[cur] + (wr * 32 + 16 + fr) * 32 + kg * 8);
    bf16x8 b[4];
#pragma unroll
    for (int ni = 0; ni < 4; ++ni)
      b[ni] = *(const bf16x8*)(sB[cur] + (wc * 64 + ni * 16 + fr) * 32 + kg * 8);
#pragma unroll
    for (int ni = 0; ni < 4; ++ni) {
      acc[0][ni] = __builtin_amdgcn_mfma_f32_16x16x32_bf16(a0, b[ni], acc[0][ni], 0, 0, 0);
      acc[1][ni] = __builtin_amdgcn_mfma_f32_16x16x32_bf16(a1, b[ni], acc[1][ni], 0, 0, 0);
    }
    __syncthreads();
    cur ^= 1;
  }

#pragma unroll
  for (int mi = 0; mi < 2; ++mi) {
#pragma unroll
    for (int j = 0; j < 4; ++j) {
      int grow = rt * 64 + wr * 32 + mi * 16 + kg * 4 + j;
      if (grow < cnt) {
        int   t = tok[e * T_TOK + grow];
        float w = wt [e * T_TOK + grow];
        float* orow = out + (size_t)t * H_DIM + nb + wc * 64 + fr;
#pragma unroll
        for (int ni = 0; ni < 4; ++ni)
          atomicAdd(orow + ni * 16, w * acc[mi][ni][j]);
      }
    }
  }
}

extern "C" void kernel_launch(void* const* d_in, const int* in_sizes, int n_in,
                              void* d_out, int out_size, void* d_ws, size_t ws_size,
                              hipStream_t stream) {
  const float* x   = (const float*)d_in[0];
  const float* gw  = (const float*)d_in[1];
  const float* wgu = (const float*)d_in[2];
  const float* wd  = (const float*)d_in[3];
  const float* sgu = (const float*)d_in[4];
  const float* sd  = (const float*)d_in[5];
  float* out = (float*)d_out;

  char* ws = (char*)d_ws;
  int*   counts = (int*)  (ws);                 // 1 KB
  int*   tok    = (int*)  (ws + 1024);          // 68 KB
  float* wtA    = (float*)(ws + 70656);         // 68 KB
  int*   slotA  = (int*)  (ws + 140288);        // 68 KB
  int*   topk_e = (int*)  (ws + 209920);        // 16 KB
  float* topk_w = (float*)(ws + 226304);        // 16 KB
  bf16*  xb     = (bf16*) (ws + 245760);        // 2 MB
  bf16*  hbuf   = (bf16*) (ws + 2342912);       // 5.25 MB
  bf16*  wguT   = (bf16*) (ws + 7585792);       // 32 MB  [E][2I][H]
  bf16*  wdT    = (bf16*) (ws + 41140224);      // 16 MB  [E][H][I]
  bf16*  sguT   = (bf16*) (ws + 57917440);      // 2 MB   [2I][H]
  bf16*  sdT    = (bf16*) (ws + 60014592);      // 1 MB   [H][I]
  // total ~61.1 MB

  init_kernel<<<1024, 256, 0, stream>>>(out, counts, tok, wtA, slotA);
  convx_kernel<<<512, 256, 0, stream>>>(x, xb);
  transpose_conv_kernel<<<dim3(16, 16, E_NUM), 256, 0, stream>>>(wgu, wguT, H_DIM, 2 * I_DIM);
  transpose_conv_kernel<<<dim3(16,  8, E_NUM), 256, 0, stream>>>(wd,  wdT,  I_DIM, H_DIM);
  transpose_conv_kernel<<<dim3(16, 16, 1),     256, 0, stream>>>(sgu, sguT, H_DIM, 2 * I_DIM);
  transpose_conv_kernel<<<dim3(16,  8, 1),     256, 0, stream>>>(sd,  sdT,  I_DIM, H_DIM);
  router_score_kernel<<<T_TOK / 4, 256, 0, stream>>>(x, gw, topk_e, topk_w);
  router_build_kernel<<<E_NUM, 256, 0, stream>>>(topk_e, topk_w, counts, tok, wtA, slotA);
  gemm1_kernel<<<dim3(8, 16, 17), 256, 0, stream>>>(xb, wguT, sguT, counts, tok, slotA, hbuf);
  gemm2_kernel<<<dim3(8, 16, 17), 256, 0, stream>>>(hbuf, wdT, sdT, counts, tok, wtA, slotA, out);
}